// Round 13
// baseline (14.089 us; speedup 1.0000x reference)
//
#include <hip/hip_runtime.h>
#include <math.h>

// SMorphLayer via f16 MFMA implicit-GEMM, pair-major K layout.
// B=8,C=1,H=W=128,F=16,K=5x5 -> 124x124.
// y[b,f,oy,ox] = n1/d1 + n2/d2 + bias[f]; features {E,pE,I,pI} (f16).
// K-order (valid since A and B share it): k = P*8 + u*4 + c, pair P=kh*3+pr
// covering taps (kh, 2pr) [u=0] and (kh, 2pr+1) [u=1]; pr=2 upper and pair 15
// have ZERO B weights (A reads garbage-but-finite there -> contributes 0).
// Per-lane A fragment (step kk) = pair P=kk*4+half = two adjacent f16x4 in
// feat -> one ds_read2_b64-class access, no masks.
// n-cols: 0..15=n1_f | 16..31=d1_f | 32..47=n2_f | 48..63=d2_f.

#define Bn 8
#define Fn 16
#define Hn 128
#define Wn 128
#define OHn 124
#define OWn 124
#define OY 4
#define FR 9                 // 8 staged rows + zero row 8 (wrap guard)
#define FC 68

typedef _Float16 f16;
typedef __attribute__((ext_vector_type(8))) _Float16 f16x8;
typedef __attribute__((ext_vector_type(4))) _Float16 f16x4;
typedef __attribute__((ext_vector_type(4))) float f4_t;

__global__ __launch_bounds__(256) void smorph_mfma(
    const float* __restrict__ x, const float* __restrict__ k1,
    const float* __restrict__ k2, const float* __restrict__ bias,
    float* __restrict__ out) {
  __shared__ __align__(16) f16 Bt[64][128];            // 16 KB
  __shared__ __align__(16) f16 feat[(FR * FC + 1) * 4]; // 4904 B (+guard)

  const int tid = threadIdx.x;
  const int b = blockIdx.z;
  const int oy0 = blockIdx.y * OY;
  const int ox0 = blockIdx.x ? (OWn - 64) : 0;  // strips {0,60}; overlap cols
                                                // written with identical values

  // ---- stage weights: one b128 per (n,P); 1024 iters = 4/thread ----
  for (int i = tid; i < 1024; i += 256) {
    const int n = i & 63, P = i >> 6;          // n fixed per thread; P varies
    const int g = n >> 4, f = n & 15;
    f16x8 w = {0, 0, 0, 0, 0, 0, 0, 0};
    if (P < 15) {
      const int kh = P / 3, pr = P - kh * 3;
      const int j = kh * 5 + 2 * pr;
      const bool up = (pr < 2);
      const float a0 = k1[f * 25 + j],            c0 = k2[f * 25 + j];
      const float a1 = up ? k1[f * 25 + j + 1] : 0.f;
      const float c1 = up ? k2[f * 25 + j + 1] : 0.f;
      const float e10 = __expf(a0), e20 = __expf(c0);
      const float e11 = up ? __expf(a1) : 0.f, e21 = up ? __expf(c1) : 0.f;
      if (g == 0) {        // n1: c0->k1*e1, c1->e1
        w[0] = (f16)(a0 * e10); w[1] = (f16)e10;
        w[4] = (f16)(a1 * e11); w[5] = (f16)e11;
      } else if (g == 1) { // d1: c0->e1
        w[0] = (f16)e10;        w[4] = (f16)e11;
      } else if (g == 2) { // n2: c2->k2*e2, c3->-e2
        w[2] = (f16)(c0 * e20); w[3] = (f16)(-e20);
        w[6] = (f16)(c1 * e21); w[7] = (f16)(-e21);
      } else {             // d2: c2->e2
        w[2] = (f16)e20;        w[6] = (f16)e21;
      }
    }
    *(f16x8*)&Bt[n][P * 8] = w;
  }

  // ---- stage features rows 0..7 (in-bounds: oy0<=120, ox0+67<=127) ----
  const float* xb = x + (b * Hn + oy0) * Wn + ox0;
  for (int i = tid; i < 8 * FC; i += 256) {
    const int r = i / FC, cpos = i % FC;
    const float p = xb[r * Wn + cpos];
    const float E = __expf(p), I = __expf(-p);
    f16x4 v;
    v[0] = (f16)E; v[1] = (f16)(p * E); v[2] = (f16)I; v[3] = (f16)(p * I);
    *(f16x4*)&feat[i * 4] = v;
  }
  // zero row 8 + guard slot (row-wrap reads land here; must be finite)
  if (tid < FC + 1) {
    const f16x4 z = {0, 0, 0, 0};
    *(f16x4*)&feat[(8 * FC + tid) * 4] = z;
  }
  __syncthreads();  // the only barrier

  // ---- per-wave: 16 px x 64 ch x OY rows ----
  const int lane = tid & 63, wv = tid >> 6;
  const int mh = lane & 15;      // A row (pixel) on loads; D col (chan) on out
  const int half = lane >> 4;
  const int px = wv * 16 + mh;

  // hoist B fragments (64 VGPRs), reused all rounds
  f16x8 Bf[4][4];
#pragma unroll
  for (int kk = 0; kk < 4; ++kk)
#pragma unroll
    for (int nt = 0; nt < 4; ++nt)
      Bf[kk][nt] = *(const f16x8*)&Bt[nt * 16 + mh][kk * 32 + half * 8];

  // A base addresses: pair P = kk*4 + half
  int taddr[4];
#pragma unroll
  for (int kk = 0; kk < 4; ++kk) {
    const int P = kk * 4 + half;
    const int kh = P / 3, pr = P - kh * 3;
    taddr[kk] = (P == 15) ? 0 : (kh * FC + px + 2 * pr) * 4;
  }

  const float bv = bias[mh];
  const int pxcol = ox0 + wv * 16 + half * 4;

#pragma unroll 1
  for (int r = 0; r < OY; ++r) {
    const int roff = r * (FC * 4);
    f4_t acc0 = {0,0,0,0}, acc1 = {0,0,0,0}, acc2 = {0,0,0,0}, acc3 = {0,0,0,0};
#pragma unroll
    for (int kk = 0; kk < 4; ++kk) {
      const int base = taddr[kk] + roff;
      const f16x4 a0 = *(const f16x4*)&feat[base];
      const f16x4 a1 = *(const f16x4*)&feat[base + 4];
      const f16x8 A = __builtin_shufflevector(a0, a1, 0, 1, 2, 3, 4, 5, 6, 7);
      acc0 = __builtin_amdgcn_mfma_f32_16x16x32_f16(A, Bf[kk][0], acc0, 0, 0, 0);
      acc1 = __builtin_amdgcn_mfma_f32_16x16x32_f16(A, Bf[kk][1], acc1, 0, 0, 0);
      acc2 = __builtin_amdgcn_mfma_f32_16x16x32_f16(A, Bf[kk][2], acc2, 0, 0, 0);
      acc3 = __builtin_amdgcn_mfma_f32_16x16x32_f16(A, Bf[kk][3], acc3, 0, 0, 0);
    }
    f4_t o;
#pragma unroll
    for (int j = 0; j < 4; ++j)
      o[j] = __fdividef(acc0[j], acc1[j]) + __fdividef(acc2[j], acc3[j]) + bv;
    *(f4_t*)&out[((b * Fn + mh) * OHn + (oy0 + r)) * OWn + pxcol] = o;
  }
}

extern "C" void kernel_launch(void* const* d_in, const int* in_sizes, int n_in,
                              void* d_out, int out_size, void* d_ws, size_t ws_size,
                              hipStream_t stream) {
  const float* x    = (const float*)d_in[0];
  const float* k1   = (const float*)d_in[1];
  const float* k2   = (const float*)d_in[2];
  const float* bias = (const float*)d_in[3];
  float* out = (float*)d_out;

  dim3 grid(2, OHn / OY, Bn);  // (2, 31, 8) = 496 blocks, fully co-resident
  smorph_mfma<<<grid, 256, 0, stream>>>(x, k1, k2, bias, out);
}

// Round 14
// 11.403 us; speedup vs baseline: 1.2355x; 1.2355x over previous
//
#include <hip/hip_runtime.h>
#include <math.h>

// SMorphLayer via f16 MFMA implicit-GEMM (round-11 structure + LDS de-conflict).
// B=8,C=1,H=W=128,F=16,K=5 -> 124x124.
// y[b,f,oy,ox] = n1/d1 + n2/d2 + bias[f]; per-tap features {E,pE,I,pI} (f16);
// weights W[k=tap*4+c][n]: n 0..15=n1 | 16..31=d1 | 32..47=n2 | 48..63=d2.
//
// Round-13 theory: Bt row stride 256B == 0 mod 32 banks -> every row-varying
// access (Bf hoist reads rows nt*16+mh same col: 16-way; weight-build stores
// rows f,16+f,32+f,48+f: 16-way) serialized on banks 0-3, ~3-6us/dispatch
// (m136: 16-way = 5.7x). Fix: pad rows to 136 f16 (272B = +4 banks/row ->
// ~2-way, free) and reindex build to i=f*25+j (lanes vary j -> ~4-way;
// k1/k2 reads become coalesced). Everything else identical to round 11.

#define Bn 8
#define Fn 16
#define Hn 128
#define Wn 128
#define OHn 124
#define OWn 124
#define OY 4
#define FR (OY + 4)          // feature rows staged = 8
#define FC 68                // feature cols staged
#define ZSLOT (FR * FC * 4)  // zero-slot element index in feat
#define BTW 136              // Bt row stride in f16 (272B: bank-spread pad)

typedef _Float16 f16;
typedef __attribute__((ext_vector_type(8))) _Float16 f16x8;
typedef __attribute__((ext_vector_type(4))) _Float16 f16x4;
typedef __attribute__((ext_vector_type(4))) float f4_t;

__global__ __launch_bounds__(256) void smorph_mfma(
    const float* __restrict__ x, const float* __restrict__ k1,
    const float* __restrict__ k2, const float* __restrict__ bias,
    float* __restrict__ out) {
  __shared__ __align__(16) f16 Bt[64][BTW];        // 17408 B
  __shared__ __align__(16) f16 feat[ZSLOT + 4];    // 4360 B (+zero slot)

  const int tid = threadIdx.x;
  const int b = blockIdx.z;
  const int oy0 = blockIdx.y * OY;
  const int ox0 = blockIdx.x ? (OWn - 64) : 0;  // strips {0,60}; overlap cols
                                                // written with identical values

  // ---- stage weights: i = f*25 + j (linear: coalesced k1/k2, j-varying
  //      lanes -> bank-spread stores with the padded row) ----
  for (int i = tid; i < 400; i += 256) {
    const int f = i / 25, j = i - f * 25;
    const float a = k1[i], c = k2[i];
    const float e1 = __expf(a), e2 = __expf(c);
    f16x4 r0; r0[0] = (f16)(a * e1); r0[1] = (f16)e1; r0[2] = (f16)0; r0[3] = (f16)0;
    f16x4 r1; r1[0] = (f16)e1;       r1[1] = (f16)0;  r1[2] = (f16)0; r1[3] = (f16)0;
    f16x4 r2; r2[0] = (f16)0; r2[1] = (f16)0; r2[2] = (f16)(c * e2); r2[3] = (f16)(-e2);
    f16x4 r3; r3[0] = (f16)0; r3[1] = (f16)0; r3[2] = (f16)e2;       r3[3] = (f16)0;
    *(f16x4*)&Bt[f     ][j * 4] = r0;
    *(f16x4*)&Bt[16 + f][j * 4] = r1;
    *(f16x4*)&Bt[32 + f][j * 4] = r2;
    *(f16x4*)&Bt[48 + f][j * 4] = r3;
  }
  // zero the K-tail (cols 100..127; pad cols 128..135 never read)
  {
    const f16x4 z = {0, 0, 0, 0};
    for (int i = tid; i < 64 * 7; i += 256) {        // 7 b64 per row
      const int row = i / 7, c8 = i % 7;
      *(f16x4*)&Bt[row][100 + c8 * 4] = z;
    }
    if (tid == 0) *(f16x4*)&feat[ZSLOT] = z;
  }
  // ---- stage features: rows oy0..oy0+7, cols ox0..ox0+67 (in-bounds) ----
  const float* xb = x + (b * Hn + oy0) * Wn + ox0;
  for (int i = tid; i < FR * FC; i += 256) {
    const int r = i / FC, cpos = i % FC;
    const float p = xb[r * Wn + cpos];
    const float E = __expf(p), I = __expf(-p);
    f16x4 v;
    v[0] = (f16)E; v[1] = (f16)(p * E); v[2] = (f16)I; v[3] = (f16)(p * I);
    *(f16x4*)&feat[i * 4] = v;
  }
  __syncthreads();  // the only barrier

  // ---- per-wave: 16 px x 64 ch x OY rows ----
  const int lane = tid & 63, wv = tid >> 6;
  const int mh = lane & 15;      // A row (pixel) in loads; D col (chan) on out
  const int half = lane >> 4;

  // hoist B fragments: Bf[kk][nt], 64 VGPRs, reused all rounds
  // (padded rows: banks spread ~2-way instead of 16-way)
  f16x8 Bf[4][4];
#pragma unroll
  for (int kk = 0; kk < 4; ++kk)
#pragma unroll
    for (int nt = 0; nt < 4; ++nt)
      Bf[kk][nt] = *(const f16x8*)&Bt[nt * 16 + mh][kk * 32 + half * 8];

  // A-tap element addresses (t = kk*8 + half*2 + s); -1 -> zero slot
  int taddr[8];
#pragma unroll
  for (int kk = 0; kk < 4; ++kk)
#pragma unroll
    for (int s = 0; s < 2; ++s) {
      const int t = kk * 8 + half * 2 + s;
      const int kh = t / 5, kw = t - kh * 5;
      taddr[kk * 2 + s] = (t < 25) ? (kh * FC + (wv * 16 + mh) + kw) * 4 : -1;
    }

  const float bv = bias[mh];
  const int pxcol = ox0 + wv * 16 + half * 4;

#pragma unroll 1
  for (int r = 0; r < OY; ++r) {
    const int roff = r * (FC * 4);
    f4_t acc0 = {0,0,0,0}, acc1 = {0,0,0,0}, acc2 = {0,0,0,0}, acc3 = {0,0,0,0};
#pragma unroll
    for (int kk = 0; kk < 4; ++kk) {
      const int i0 = taddr[kk * 2], i1 = taddr[kk * 2 + 1];
      const f16x4 a0 = *(const f16x4*)&feat[(i0 < 0) ? ZSLOT : i0 + roff];
      const f16x4 a1 = *(const f16x4*)&feat[(i1 < 0) ? ZSLOT : i1 + roff];
      const f16x8 A = __builtin_shufflevector(a0, a1, 0, 1, 2, 3, 4, 5, 6, 7);
      acc0 = __builtin_amdgcn_mfma_f32_16x16x32_f16(A, Bf[kk][0], acc0, 0, 0, 0);
      acc1 = __builtin_amdgcn_mfma_f32_16x16x32_f16(A, Bf[kk][1], acc1, 0, 0, 0);
      acc2 = __builtin_amdgcn_mfma_f32_16x16x32_f16(A, Bf[kk][2], acc2, 0, 0, 0);
      acc3 = __builtin_amdgcn_mfma_f32_16x16x32_f16(A, Bf[kk][3], acc3, 0, 0, 0);
    }
    f4_t o;
#pragma unroll
    for (int j = 0; j < 4; ++j)
      o[j] = __fdividef(acc0[j], acc1[j]) + __fdividef(acc2[j], acc3[j]) + bv;
    *(f4_t*)&out[((b * Fn + mh) * OHn + (oy0 + r)) * OWn + pxcol] = o;
  }
}

extern "C" void kernel_launch(void* const* d_in, const int* in_sizes, int n_in,
                              void* d_out, int out_size, void* d_ws, size_t ws_size,
                              hipStream_t stream) {
  const float* x    = (const float*)d_in[0];
  const float* k1   = (const float*)d_in[1];
  const float* k2   = (const float*)d_in[2];
  const float* bias = (const float*)d_in[3];
  float* out = (float*)d_out;

  dim3 grid(2, OHn / OY, Bn);  // (2, 31, 8) = 496 blocks, fully co-resident
  smorph_mfma<<<grid, 256, 0, stream>>>(x, k1, k2, bias, out);
}